// Round 9
// baseline (3382.000 us; speedup 1.0000x reference)
//
#include <hip/hip_runtime.h>

// LSTM_38869454028951: B=512, T=365, F=16, H=256, 2 layers + linear head.
// Round 9: exchange-path surgery on the r6 skeleton (16bg x 16ns, 512thr,
// gp x kq wave map, merged GEMM). Changes:
//  - B2 rendezvous removed: per-WAVE vmcnt drain + lane0 counter add
//    (128 adds/clique/body), per-wave polling (no 8192-thread spin storm).
//  - h published as TWO bf16 slabs (hi,lo) via asm global_store_short sc0 sc1;
//    restage = straight u64 loads -> ushort8 LDS copies (zero unpack VALU).
//  - 2 barriers/body (B1 zb, B3 A-staged).

#define T_STEPS 365
#define ASTR 552   // A row stride (ushorts)

typedef __attribute__((ext_vector_type(8))) short short8;
typedef __attribute__((ext_vector_type(8))) unsigned short ushort8;
typedef __attribute__((ext_vector_type(4))) float float4_;
typedef unsigned long long u64;
typedef unsigned int u32;

#define MFMA16(a, b, c) __builtin_amdgcn_mfma_f32_16x16x32_bf16((a), (b), (c), 0, 0, 0)
// zb layout: [gate 4][kq 4][col 16][row 36pad]
#define ZBI(G, Q, C, R) (((((G) * 4 + (Q)) * 16 + (C)) * 36) + (R))

__device__ __forceinline__ unsigned short f2bf(float v) {
    union { float f; u32 u; } a; a.f = v;
    u32 r = a.u + 0x7fffu + ((a.u >> 16) & 1u);  // RNE
    return (unsigned short)(r >> 16);
}
__device__ __forceinline__ float bf2f(unsigned short h) {
    union { u32 u; float f; } a; a.u = ((u32)h) << 16; return a.f;
}
__device__ __forceinline__ float sigm(float x)  { return 1.f / (1.f + __expf(-x)); }
__device__ __forceinline__ float tanh_(float x) { return 2.f / (1.f + __expf(-2.f * x)) - 1.f; }

__device__ __forceinline__ void poll_ge(u32* c, u32 tgt) {
    while (__hip_atomic_load(c, __ATOMIC_RELAXED, __HIP_MEMORY_SCOPE_AGENT) < tgt)
        __builtin_amdgcn_s_sleep(1);
}
__device__ __forceinline__ void vmwait0() { asm volatile("s_waitcnt vmcnt(0)" ::: "memory"); }
// 2B store, agent-coherent (bypass non-coherent L2 to coherence point)
__device__ __forceinline__ void gstore2(unsigned short* p, u32 v) {
    asm volatile("global_store_short %0, %1, off sc0 sc1" :: "v"(p), "v"(v) : "memory");
}

// ---------------- prep: blocked hi/lo weights + biases ----------------
// w1blk: [64 tiles][9 ks][16 rows][32 k]; ks<8: Whh1; ks==8: Wih1 (K pad 16->32)
// w2blk: [64][16][16][32]; ks<8: Wih2 (h1 input), ks>=8: Whh2 (h2 input)
__global__ void prep_w(
    const float* __restrict__ Wih1, const float* __restrict__ Whh1,
    const float* __restrict__ bih1, const float* __restrict__ bhh1,
    const float* __restrict__ Wih2, const float* __restrict__ Whh2,
    const float* __restrict__ bih2, const float* __restrict__ bhh2,
    unsigned short* __restrict__ w1h, unsigned short* __restrict__ w1l,
    unsigned short* __restrict__ w2h, unsigned short* __restrict__ w2l,
    float* __restrict__ bias1, float* __restrict__ bias2)
{
    const int tile = blockIdx.x;          // 64
    const int g = tile >> 4, ns = tile & 15;
    const int tid = threadIdx.x;          // 256

    for (int idx = tid; idx < 9 * 512; idx += 256) {
        int ks = idx >> 9, off = idx & 511, r = off >> 5, kk = off & 31;
        int R = g * 256 + ns * 16 + r;
        float v;
        if (ks < 8)       v = Whh1[R * 256 + ks * 32 + kk];
        else if (kk < 16) v = Wih1[R * 16 + kk];
        else              v = 0.f;
        unsigned short h = f2bf(v);
        size_t d = (size_t)(tile * 9 + ks) * 512 + off;
        w1h[d] = h; w1l[d] = f2bf(v - bf2f(h));
    }
    for (int idx = tid; idx < 16 * 512; idx += 256) {
        int ks = idx >> 9, off = idx & 511, r = off >> 5, kk = off & 31;
        int R = g * 256 + ns * 16 + r;
        int k = ks * 32 + kk;
        float v = (k < 256) ? Wih2[R * 256 + k] : Whh2[R * 256 + (k - 256)];
        unsigned short h = f2bf(v);
        size_t d = (size_t)(tile * 16 + ks) * 512 + off;
        w2h[d] = h; w2l[d] = f2bf(v - bf2f(h));
    }
    if (tid < 16) {
        int R = g * 256 + ns * 16 + tid;
        bias1[R] = bih1[R] + bhh1[R];
        bias2[R] = bih2[R] + bhh2[R];
    }
}

// copy 16 bf16 (32B) from an agent-coherent slab to LDS, no unpack
__device__ __forceinline__ void stage32c(const unsigned short* src, unsigned short* dst) {
    union { u64 q[2]; ushort8 s; } a, b;
    a.q[0] = __hip_atomic_load((const u64*)src + 0, __ATOMIC_RELAXED, __HIP_MEMORY_SCOPE_AGENT);
    a.q[1] = __hip_atomic_load((const u64*)src + 1, __ATOMIC_RELAXED, __HIP_MEMORY_SCOPE_AGENT);
    b.q[0] = __hip_atomic_load((const u64*)src + 2, __ATOMIC_RELAXED, __HIP_MEMORY_SCOPE_AGENT);
    b.q[1] = __hip_atomic_load((const u64*)src + 3, __ATOMIC_RELAXED, __HIP_MEMORY_SCOPE_AGENT);
    *(ushort8*)dst = a.s;
    *(ushort8*)(dst + 8) = b.s;
}

// ---------------- main ----------------
__global__ __launch_bounds__(512, 2) void lstm_main(
    const float* __restrict__ x,
    const unsigned short* __restrict__ w1h, const unsigned short* __restrict__ w1l,
    const unsigned short* __restrict__ w2h, const unsigned short* __restrict__ w2l,
    const float* __restrict__ bias1, const float* __restrict__ bias2,
    unsigned short* hb1h, unsigned short* hb1l,
    unsigned short* hb2h, unsigned short* hb2l,
    u32* prog,
    const float* __restrict__ Wlin, const float* __restrict__ blin,
    float* __restrict__ out)
{
    // A cols: [0..255]=h1_{t-1}, [256..287]=x_t (272+ zero), [288..543]=h2_{t-2}
    __shared__ __align__(16) unsigned short A2h[32][ASTR];
    __shared__ __align__(16) unsigned short A2l[32][ASTR];
    __shared__ __align__(16) float zb1f[4 * 4 * 16 * 36];
    __shared__ __align__(16) float zb2f[4 * 4 * 16 * 36];
    __shared__ __align__(16) float hp[32][17];

    const int tid  = threadIdx.x;
    const int lane = tid & 63;
    const int wv   = tid >> 6;            // 8 waves
    const int quad = lane >> 4;
    const int r16  = lane & 15;
    const int kq   = wv & 3;              // K-quarter
    const int gp   = wv >> 2;             // gate pair: gates {2gp, 2gp+1}
    const int bg   = blockIdx.x & 15;     // batch group
    const int ns   = blockIdx.x >> 4;     // col slice
    const int loff = r16 * 32 + quad * 8;

    const int urow = tid >> 4;            // updater: batch row 0..31 (wave w owns 4w..4w+3)
    const int ucol = tid & 15;            // local col 0..15
    const int colg = ns * 16 + ucol;      // global hidden col

    u32* cnt = prog + bg * 32;

    float bi1[4], bi2[4];
#pragma unroll
    for (int gg = 0; gg < 4; gg++) {
        bi1[gg] = bias1[gg * 256 + colg];
        bi2[gg] = bias2[gg * 256 + colg];
    }

    // ---- weight fragment preload (compiler may re-stream from L2; proven neutral) ----
    short8 W1H[2][3], W1L[2][3], W2H[2][4], W2L[2][4];
#pragma unroll
    for (int gg = 0; gg < 2; gg++) {
        const int tl = (gp * 2 + gg) * 16 + ns;
        const unsigned short* b1h = w1h + (size_t)tl * 9 * 512;
        const unsigned short* b1l = w1l + (size_t)tl * 9 * 512;
        const unsigned short* b2h = w2h + (size_t)tl * 16 * 512;
        const unsigned short* b2l = w2l + (size_t)tl * 16 * 512;
#pragma unroll
        for (int j = 0; j < 2; j++) {
            const int ks = 2 * kq + j;
            W1H[gg][j] = *(const short8*)(b1h + (size_t)ks * 512 + loff);
            W1L[gg][j] = *(const short8*)(b1l + (size_t)ks * 512 + loff);
        }
        if (kq == 3) {   // x weights (Wih1, ks=8)
            W1H[gg][2] = *(const short8*)(b1h + (size_t)8 * 512 + loff);
            W1L[gg][2] = *(const short8*)(b1l + (size_t)8 * 512 + loff);
        } else {
            W1H[gg][2] = short8{0,0,0,0,0,0,0,0};
            W1L[gg][2] = short8{0,0,0,0,0,0,0,0};
        }
#pragma unroll
        for (int j = 0; j < 2; j++) {
            const int ksA = 2 * kq + j;        // Wih2 (h1 input)
            const int ksB = 8 + 2 * kq + j;    // Whh2 (h2 input)
            W2H[gg][j]     = *(const short8*)(b2h + (size_t)ksA * 512 + loff);
            W2L[gg][j]     = *(const short8*)(b2l + (size_t)ksA * 512 + loff);
            W2H[gg][2 + j] = *(const short8*)(b2h + (size_t)ksB * 512 + loff);
            W2L[gg][2 + j] = *(const short8*)(b2l + (size_t)ksB * 512 + loff);
        }
    }

    // ---- zero A LDS; stage x_0 ----
    for (int i = tid; i < 32 * ASTR; i += 512) { (&A2h[0][0])[i] = 0; (&A2l[0][0])[i] = 0; }
    __syncthreads();
    {
        float v = x[((size_t)(bg * 32 + urow) * T_STEPS + 0) * 16 + ucol];
        unsigned short h = f2bf(v);
        A2h[urow][256 + ucol] = h;
        A2l[urow][256 + ucol] = f2bf(v - bf2f(h));
    }
    __syncthreads();

    float c1 = 0.f, c2 = 0.f;

#define TERM3(A0, A1, WHR, WLR)                                \
    A0 = MFMA16(ah0, WHR, A0); A1 = MFMA16(ah1, WHR, A1);      \
    A0 = MFMA16(al0, WHR, A0); A1 = MFMA16(al1, WHR, A1);      \
    A0 = MFMA16(ah0, WLR, A0); A1 = MFMA16(ah1, WLR, A1);

    for (int t = 0; t <= T_STEPS; t++) {   // 366 bodies
        const int p = t & 1;

        // ================= merged GEMM (z1: K=288, z2: K=512) =================
        float4_ z1a[2][2] = {{{0.f,0.f,0.f,0.f},{0.f,0.f,0.f,0.f}},
                             {{0.f,0.f,0.f,0.f},{0.f,0.f,0.f,0.f}}};
        float4_ z2a[2][2] = {{{0.f,0.f,0.f,0.f},{0.f,0.f,0.f,0.f}},
                             {{0.f,0.f,0.f,0.f},{0.f,0.f,0.f,0.f}}};

#pragma unroll
        for (int j = 0; j < 2; j++) {      // h1 blocks: feed BOTH z1 and z2
            const int co = (2 * kq + j) * 32 + quad * 8;
            short8 ah0 = *(const short8*)&A2h[r16][co];
            short8 al0 = *(const short8*)&A2l[r16][co];
            short8 ah1 = *(const short8*)&A2h[r16 + 16][co];
            short8 al1 = *(const short8*)&A2l[r16 + 16][co];
#pragma unroll
            for (int gg = 0; gg < 2; gg++) {
                TERM3(z1a[gg][0], z1a[gg][1], W1H[gg][j], W1L[gg][j])
                TERM3(z2a[gg][0], z2a[gg][1], W2H[gg][j], W2L[gg][j])
            }
        }
        if (kq == 3) {                     // x block -> z1
            const int co = 256 + quad * 8;
            short8 ah0 = *(const short8*)&A2h[r16][co];
            short8 al0 = *(const short8*)&A2l[r16][co];
            short8 ah1 = *(const short8*)&A2h[r16 + 16][co];
            short8 al1 = *(const short8*)&A2l[r16 + 16][co];
#pragma unroll
            for (int gg = 0; gg < 2; gg++) {
                TERM3(z1a[gg][0], z1a[gg][1], W1H[gg][2], W1L[gg][2])
            }
        }
#pragma unroll
        for (int j = 0; j < 2; j++) {      // h2 blocks -> z2
            const int co = 288 + (2 * kq + j) * 32 + quad * 8;
            short8 ah0 = *(const short8*)&A2h[r16][co];
            short8 al0 = *(const short8*)&A2l[r16][co];
            short8 ah1 = *(const short8*)&A2h[r16 + 16][co];
            short8 al1 = *(const short8*)&A2l[r16 + 16][co];
#pragma unroll
            for (int gg = 0; gg < 2; gg++) {
                TERM3(z2a[gg][0], z2a[gg][1], W2H[gg][2 + j], W2L[gg][2 + j])
            }
        }

#pragma unroll
        for (int gg = 0; gg < 2; gg++) {
            const int gate = gp * 2 + gg;
            *(float4_*)&zb1f[ZBI(gate, kq, r16, quad * 4)]      = z1a[gg][0];
            *(float4_*)&zb1f[ZBI(gate, kq, r16, 16 + quad * 4)] = z1a[gg][1];
            *(float4_*)&zb2f[ZBI(gate, kq, r16, quad * 4)]      = z2a[gg][0];
            *(float4_*)&zb2f[ZBI(gate, kq, r16, 16 + quad * 4)] = z2a[gg][1];
        }
        __syncthreads();   // B1: zb ready; all A reads done

        // ---- reduce kq partials; update h1_t and h2_{t-1}; publish bf16 hi/lo ----
        {
            float zg1[4], zg2[4];
#pragma unroll
            for (int g4 = 0; g4 < 4; g4++) {
                float s1 = bi1[g4], s2 = bi2[g4];
#pragma unroll
                for (int q = 0; q < 4; q++) {
                    s1 += zb1f[ZBI(g4, q, ucol, urow)];
                    s2 += zb2f[ZBI(g4, q, ucol, urow)];
                }
                zg1[g4] = s1; zg2[g4] = s2;
            }
            const size_t o1 = (((size_t)p * 16 + bg) * 32 + urow) * 256 + colg;
            const size_t o2 = (((size_t)(1 - p) * 16 + bg) * 32 + urow) * 256 + colg;
            if (t <= T_STEPS - 1) {   // layer 1 -> h1_t
                c1 = sigm(zg1[1]) * c1 + sigm(zg1[0]) * tanh_(zg1[2]);
                float h1v = sigm(zg1[3]) * tanh_(c1);
                unsigned short hi = f2bf(h1v);
                unsigned short lo = f2bf(h1v - bf2f(hi));
                gstore2(&hb1h[o1], hi);
                gstore2(&hb1l[o1], lo);
            }
            {   // layer 2 -> h2_{t-1} (retimed)
                float nc2 = sigm(zg2[1]) * c2 + sigm(zg2[0]) * tanh_(zg2[2]);
                float h2v = sigm(zg2[3]) * tanh_(nc2);
                if (t == 0) { nc2 = 0.f; h2v = 0.f; }   // h2_{-1} = 0
                c2 = nc2;
                unsigned short hi = f2bf(h2v);
                unsigned short lo = f2bf(h2v - bf2f(hi));
                gstore2(&hb2h[o2], hi);
                gstore2(&hb2l[o2], lo);
            }
        }

        // ---- per-WAVE signal: own stores ack'd -> lane0 adds (no WG barrier) ----
        vmwait0();
        if (lane == 0)
            __hip_atomic_fetch_add(cnt, 1u, __ATOMIC_RELAXED, __HIP_MEMORY_SCOPE_AGENT);

        // ---- prefetch x_{t+1} into A block 8 (own rows; GEMM reads done at B1) ----
        {
            int tn = (t + 1 <= T_STEPS - 1) ? t + 1 : T_STEPS - 1;
            float v = x[((size_t)(bg * 32 + urow) * T_STEPS + tn) * 16 + ucol];
            unsigned short h = f2bf(v);
            A2h[urow][256 + ucol] = h;
            A2l[urow][256 + ucol] = f2bf(v - bf2f(h));
        }

        // ---- per-wave poll: 128 adds/body expected; then restage own rows ----
        poll_ge(cnt, (u32)(128 * (t + 1)));
        {
            const size_t s1 = (((size_t)p * 16 + bg) * 32 + urow) * 256 + ucol * 16;
            const size_t s2 = (((size_t)(1 - p) * 16 + bg) * 32 + urow) * 256 + ucol * 16;
            stage32c(hb1h + s1, &A2h[urow][ucol * 16]);
            stage32c(hb1l + s1, &A2l[urow][ucol * 16]);
            stage32c(hb2h + s2, &A2h[urow][288 + ucol * 16]);
            stage32c(hb2l + s2, &A2l[urow][288 + ucol * 16]);
        }
        __syncthreads();   // B3: A ready for next body
    }

    // ---- head (ns==0): out[b] = h2_364 . Wlin + blin ; h2_364 in slot 0 ----
    if (ns != 0) return;
    {
        int row = tid >> 4, seg = tid & 15;
        const size_t o = ((size_t)bg * 32 + row) * 256 + seg * 16;   // slot 0
        union { u64 q[4]; unsigned short s[16]; } vh, vl;
#pragma unroll
        for (int j = 0; j < 4; j++) {
            vh.q[j] = __hip_atomic_load((const u64*)(hb2h + o) + j, __ATOMIC_RELAXED, __HIP_MEMORY_SCOPE_AGENT);
            vl.q[j] = __hip_atomic_load((const u64*)(hb2l + o) + j, __ATOMIC_RELAXED, __HIP_MEMORY_SCOPE_AGENT);
        }
        float s = 0.f;
#pragma unroll
        for (int j = 0; j < 16; j++)
            s += (bf2f(vh.s[j]) + bf2f(vl.s[j])) * Wlin[seg * 16 + j];
        hp[row][seg] = s;
    }
    __syncthreads();
    if (tid < 32) {
        float s = 0.f;
#pragma unroll
        for (int j = 0; j < 16; j++) s += hp[tid][j];
        out[bg * 32 + tid] = s + blin[0];
    }
}

extern "C" void kernel_launch(void* const* d_in, const int* in_sizes, int n_in,
                              void* d_out, int out_size, void* d_ws, size_t ws_size,
                              hipStream_t stream) {
    const float* x    = (const float*)d_in[0];
    const float* Wih1 = (const float*)d_in[1];
    const float* Whh1 = (const float*)d_in[2];
    const float* bih1 = (const float*)d_in[3];
    const float* bhh1 = (const float*)d_in[4];
    const float* Wih2 = (const float*)d_in[5];
    const float* Whh2 = (const float*)d_in[6];
    const float* bih2 = (const float*)d_in[7];
    const float* bhh2 = (const float*)d_in[8];
    const float* Wlin = (const float*)d_in[9];
    const float* blin = (const float*)d_in[10];
    float* out = (float*)d_out;

    char* pp = (char*)d_ws;
    unsigned short* w1h = (unsigned short*)pp; pp += (size_t)64 * 9 * 512 * 2;
    unsigned short* w1l = (unsigned short*)pp; pp += (size_t)64 * 9 * 512 * 2;
    unsigned short* w2h = (unsigned short*)pp; pp += (size_t)64 * 16 * 512 * 2;
    unsigned short* w2l = (unsigned short*)pp; pp += (size_t)64 * 16 * 512 * 2;
    float* bias1 = (float*)pp; pp += 1024 * 4;
    float* bias2 = (float*)pp; pp += 1024 * 4;
    char* zero_base = pp;
    unsigned short* hb1h = (unsigned short*)pp; pp += (size_t)2 * 16 * 32 * 256 * 2;  // 512 KB
    unsigned short* hb1l = (unsigned short*)pp; pp += (size_t)2 * 16 * 32 * 256 * 2;
    unsigned short* hb2h = (unsigned short*)pp; pp += (size_t)2 * 16 * 32 * 256 * 2;
    unsigned short* hb2l = (unsigned short*)pp; pp += (size_t)2 * 16 * 32 * 256 * 2;
    u32* prog = (u32*)pp; pp += 16 * 32 * 4;                    // 1 counter/bg, 128B apart
    size_t zero_bytes = (size_t)(pp - zero_base);

    hipMemsetAsync(zero_base, 0, zero_bytes, stream);
    prep_w<<<64, 256, 0, stream>>>(Wih1, Whh1, bih1, bhh1, Wih2, Whh2, bih2, bhh2,
                                   w1h, w1l, w2h, w2l, bias1, bias2);
    lstm_main<<<256, 512, 0, stream>>>(x, w1h, w1l, w2h, w2l, bias1, bias2,
                                       hb1h, hb1l, hb2h, hb2l, prog, Wlin, blin, out);
}